// Round 13
// baseline (341.493 us; speedup 1.0000x reference)
//
#include <hip/hip_runtime.h>
#include <math.h>

#define NATOMS 10000
#define NEDGES 320000
#define RC_F 5.0f
#define PI_F 3.14159265358979323846f

// ---- workspace layout (in floats) ----
#define WS_SEMB   0         // 12 floats
#define WS_GTOT   12        // 1 int global allocation cursor
#define WS_CNT    16        // NATOMS ints
#define WS_OFFS   10016     // NATOMS ints (run start per atom)
#define WS_CURSOR 20016     // NATOMS ints
#define WS_EIDX   30016     // NEDGES ints: packed (t<<20)|e per atom-run

// multinomial term tables (global component index 0..34)
__device__ __constant__ int   d_PWA[35] = {0, 0,0,1, 0,0,0,1,1,2, 0,0,0,0,1,1,1,2,2,3, 0,0,0,0,0,1,1,1,1,2,2,2,3,3,4};
__device__ __constant__ int   d_PWB[35] = {0, 0,1,0, 0,1,2,0,1,0, 0,1,2,3,0,1,2,0,1,0, 0,1,2,3,4,0,1,2,3,0,1,2,0,1,0};
__device__ __constant__ int   d_PWC[35] = {0, 1,0,0, 2,1,0,1,0,0, 3,2,1,0,2,1,0,1,0,0, 4,3,2,1,0,3,2,1,0,2,1,0,1,0,0};
__device__ __constant__ float d_NM[35]  = {1.f, 1.f,1.f,1.f, 1.f,2.f,1.f,2.f,2.f,1.f,
                                           1.f,3.f,3.f,1.f,3.f,6.f,3.f,3.f,3.f,1.f,
                                           1.f,4.f,6.f,4.f,1.f,4.f,12.f,12.f,4.f,6.f,12.f,6.f,4.f,4.f,1.f};
__device__ __constant__ int   d_LBLK[35]= {0, 1,1,1, 2,2,2,2,2,2, 3,3,3,3,3,3,3,3,3,3, 4,4,4,4,4,4,4,4,4,4,4,4,4,4,4};
__device__ __constant__ int   d_L6[6]   = {0,1,4,10,20,35};

__device__ __forceinline__ float siluf(float x) { return x / (1.0f + __expf(-x)); }

__device__ __forceinline__ float2 f2fma(float2 a, float2 b, float2 c) {
  return make_float2(fmaf(a.x, b.x, c.x), fmaf(a.y, b.y, c.y));
}

__device__ __forceinline__ float psel(float x, int p) {
  float x2 = x * x;
  float r = 1.0f;
  r = (p == 1) ? x : r;
  r = (p == 2) ? x2 : r;
  r = (p == 3) ? x2 * x : r;
  r = (p == 4) ? x2 * x2 : r;
  return r;
}

// ---------------- k_init ----------------
__global__ void k_init(const float* __restrict__ Ws1, const float* __restrict__ bs1,
                       const float* __restrict__ Ws2, const float* __restrict__ bs2,
                       float* __restrict__ ws)
{
  int tid = blockIdx.x * blockDim.x + threadIdx.x;
  int* cnt = (int*)(ws + WS_CNT);
  if (tid < NATOMS) cnt[tid] = 0;
  if (tid == 0) *(int*)(ws + WS_GTOT) = 0;
  if (tid < 12) {
    int t = tid >> 2, s = tid & 3;
    float acc = bs2[s];
    for (int j = 0; j < 16; j++) acc += tanhf(Ws1[t * 16 + j] + bs1[j]) * Ws2[j * 4 + s];
    ws[WS_SEMB + tid] = acc;
  }
}

// ---------------- k_hist ----------------
__global__ void k_hist(const int* __restrict__ first_atom, float* __restrict__ ws)
{
  int e = blockIdx.x * blockDim.x + threadIdx.x;
  if (e < NEDGES) {
    int* cnt = (int*)(ws + WS_CNT);
    atomicAdd(&cnt[first_atom[e]], 1);
  }
}

// ---------------- k_alloc: decentralized run allocation ----------------
// Atoms within one 256-atom alloc block get a contiguous in-order run, so any
// 4-aligned group of 4 atoms has contiguous edges in eidx (k_fused relies on this).
__global__ __launch_bounds__(256) void k_alloc(float* __restrict__ ws)
{
  const int* cnt = (const int*)(ws + WS_CNT);
  int* offs   = (int*)(ws + WS_OFFS);
  int* cursor = (int*)(ws + WS_CURSOR);
  int* gtot = (int*)(ws + WS_GTOT);
  __shared__ int wsum[4];
  __shared__ int sbase;
  int tid = threadIdx.x;
  int lane = tid & 63, wv = tid >> 6;
  int a = blockIdx.x * 256 + tid;
  bool live = (a < NATOMS);
  int c = live ? cnt[a] : 0;
  int inc = c;
  #pragma unroll
  for (int d = 1; d < 64; d <<= 1) {
    int v = __shfl_up(inc, d, 64);
    if (lane >= d) inc += v;
  }
  if (lane == 63) wsum[wv] = inc;
  __syncthreads();
  if (tid == 0) sbase = atomicAdd(gtot, wsum[0] + wsum[1] + wsum[2] + wsum[3]);
  __syncthreads();
  int woff = sbase;
  for (int w = 0; w < wv; w++) woff += wsum[w];
  int o0 = woff + inc - c;
  if (live) { offs[a] = o0; cursor[a] = o0; }
}

// ---------------- k_scatter: per-atom edge-index lists (4B/edge) ----------------
__global__ void k_scatter(const int* __restrict__ first_atom, const int* __restrict__ second_atom,
                          const int* __restrict__ species, float* __restrict__ ws)
{
  int e = blockIdx.x * blockDim.x + threadIdx.x;
  if (e < NEDGES) {
    int* cursor = (int*)(ws + WS_CURSOR);
    int* eidx   = (int*)(ws + WS_EIDX);
    int t = species[second_atom[e]];
    int pos = atomicAdd(&cursor[first_atom[e]], 1);
    eidx[pos] = e | (t << 20);
  }
}

// ---------------- k_fused: edge MLP -> LDS records -> per-wave atom accumulation + epilogue ----------------
// Block = 256 threads = 4 waves = 4 atoms (ONE atom per wave: accumulators are 27
// VGPRs held across the MLP phase; no __launch_bounds__ occupancy clause so the
// allocator can take ~110 VGPRs without spilling — the diagnosed R8 failure).
__global__ __launch_bounds__(256) void k_fused(
    const float* __restrict__ rij,
    const float* __restrict__ Wr1, const float* __restrict__ br1,
    const float* __restrict__ Wr2, const float* __restrict__ br2,
    const float* __restrict__ Wa1, const float* __restrict__ ba1,
    const float* __restrict__ Wa2, const float* __restrict__ ba2,
    const float* __restrict__ Wa3, const float* __restrict__ ba3,
    const float* __restrict__ ws, float* __restrict__ out)
{
  __shared__ __align__(16) float sE[256 * 52];   // 53.25 KB records / epilogue scratch
  int tid = threadIdx.x, lane = tid & 63, wv = tid >> 6;
  int a0 = blockIdx.x * 4;                       // NATOMS = 2500*4 exact
  int a = a0 + wv;
  const int* offs = (const int*)(ws + WS_OFFS);
  const int* cnt  = (const int*)(ws + WS_CNT);
  const int* eidx = (const int*)(ws + WS_EIDX);

  int startA = offs[a], endA = startA + cnt[a];
  int blkStart = offs[a0];
  int blkEnd   = offs[a0 + 3] + cnt[a0 + 3];     // contiguous (see k_alloc)

  const int c = lane;
  bool isc = (c < 35);
  int pa = 0, pb = 0, pcw = 0, lb = 0;
  if (isc) { pa = d_PWA[c]; pb = d_PWB[c]; pcw = d_PWC[c]; lb = d_LBLK[c]; }
  int rdir = lane - 35;
  bool isd = (rdir >= 0) && (rdir < 8);

  float2 g2[3][4];
  #pragma unroll
  for (int t2 = 0; t2 < 3; t2++)
    #pragma unroll
    for (int r = 0; r < 4; r++) g2[t2][r] = make_float2(0.f, 0.f);
  float g0[3] = {0.0f, 0.0f, 0.0f};

  for (int cb = blkStart; cb < blkEnd; cb += 256) {
    int m = blkEnd - cb; if (m > 256) m = 256;
    __syncthreads();                             // previous chunk fully consumed
    if (tid < m) {
      int packed = eidx[cb + tid];
      int e = packed & 0xFFFFF;
      float x = rij[e * 3 + 0], y = rij[e * 3 + 1], z = rij[e * 3 + 2];
      float d = sqrtf(x * x + y * y + z * z + 1e-12f);
      float invd = 1.0f / d;
      // one sin+cos; Chebyshev recurrence; fc shares cos(theta)
      float theta = (PI_F / RC_F) * d;
      float s1 = __sinf(theta), c1 = __cosf(theta);
      float fc = (d < RC_F) ? 0.5f * (c1 + 1.0f) : 0.0f;
      float bes[8];
      {
        float sq = sqrtf(2.0f / RC_F) * invd;
        float twoc = 2.0f * c1;
        float sp = 0.0f, sc = s1;
        #pragma unroll
        for (int k = 0; k < 8; k++) {
          bes[k] = sq * sc;
          float sn = twoc * sc - sp;
          sp = sc; sc = sn;
        }
      }
      // layer 1: 8 -> 64 (weights wave-uniform -> scalar loads)
      float h1[64];
      #pragma unroll
      for (int j4 = 0; j4 < 16; j4++) {
        float acc[4];
        #pragma unroll
        for (int u = 0; u < 4; u++) acc[u] = br1[j4 * 4 + u];
        #pragma unroll
        for (int k = 0; k < 8; k++) {
          #pragma unroll
          for (int u = 0; u < 4; u++) acc[u] += bes[k] * Wr1[k * 64 + j4 * 4 + u];
        }
        #pragma unroll
        for (int u = 0; u < 4; u++) h1[j4 * 4 + u] = siluf(acc[u]);
      }
      // layer 2: 64 -> 48 -> LDS record row
      float* row = sE + tid * 52;
      for (int j4 = 0; j4 < 12; j4++) {
        float acc[4];
        #pragma unroll
        for (int u = 0; u < 4; u++) acc[u] = br2[j4 * 4 + u];
        #pragma unroll
        for (int k = 0; k < 64; k++) {
          #pragma unroll
          for (int u = 0; u < 4; u++) acc[u] += h1[k] * Wr2[k * 48 + j4 * 4 + u];
        }
        *(float4*)(row + j4 * 4) = make_float4(siluf(acc[0]) * fc, siluf(acc[1]) * fc,
                                               siluf(acc[2]) * fc, siluf(acc[3]) * fc);
      }
      *(float4*)(row + 48) = make_float4(x * invd, y * invd, z * invd,
                                         __int_as_float(packed >> 20));
    }
    __syncthreads();
    // accumulation: this wave's atom's slice of the chunk (LDS broadcast reads)
    int lo = startA > cb ? startA : cb;
    int hi = endA < cb + m ? endA : cb + m;
    for (int i = lo; i < hi; i++) {
      const float* rb = sE + (i - cb) * 52;
      float4 rt = *(const float4*)(rb + 48);
      int t = __builtin_amdgcn_readfirstlane(__float_as_int(rt.w));
      if (isc) {
        float comp = psel(rt.x, pa) * psel(rt.y, pb) * psel(rt.z, pcw);
        float2 c2 = make_float2(comp, comp);
        const float2* r2 = (const float2*)(rb + 8 + 8 * lb);
        float2 q0 = r2[0], q1 = r2[1], q2 = r2[2], q3 = r2[3];
        if (t == 0) {
          g2[0][0] = f2fma(c2, q0, g2[0][0]); g2[0][1] = f2fma(c2, q1, g2[0][1]);
          g2[0][2] = f2fma(c2, q2, g2[0][2]); g2[0][3] = f2fma(c2, q3, g2[0][3]);
        } else if (t == 1) {
          g2[1][0] = f2fma(c2, q0, g2[1][0]); g2[1][1] = f2fma(c2, q1, g2[1][1]);
          g2[1][2] = f2fma(c2, q2, g2[1][2]); g2[1][3] = f2fma(c2, q3, g2[1][3]);
        } else {
          g2[2][0] = f2fma(c2, q0, g2[2][0]); g2[2][1] = f2fma(c2, q1, g2[2][1]);
          g2[2][2] = f2fma(c2, q2, g2[2][2]); g2[2][3] = f2fma(c2, q3, g2[2][3]);
        }
      } else if (isd) {
        float v = rb[rdir];
        if (t == 0) g0[0] += v; else if (t == 1) g0[1] += v; else g0[2] += v;
      }
    }
  }
  __syncthreads();                               // records dead; reuse sE as scratch

  // ---- epilogue (per wave, its own atom) ----
  float* sW = sE + wv * 1152;
  float* sG   = sW;          // 864: G[t][r][36] (col 35 = direct block)
  float* sFeat= sW + 864;    // 192
  float* sH   = sW + 1056;   // 64

  if (isc) {
    #pragma unroll
    for (int t2 = 0; t2 < 3; t2++)
      #pragma unroll
      for (int r = 0; r < 8; r++) {
        float gval = (r & 1) ? g2[t2][r >> 1].y : g2[t2][r >> 1].x;
        sG[(t2 * 8 + r) * 36 + c] = gval;
      }
  } else if (isd) {
    #pragma unroll
    for (int t2 = 0; t2 < 3; t2++) sG[(t2 * 8 + rdir) * 36 + 35] = g0[t2];
  }

  // contraction: lane owns feats {lane, lane+64, lane+128}; f=(blk*8+rr)*4+s
  int s = lane & 3;
  float se0 = ws[WS_SEMB + s], se1 = ws[WS_SEMB + 4 + s], se2 = ws[WS_SEMB + 8 + s];
  float fout[3];
  #pragma unroll
  for (int u = 0; u < 3; u++) {
    int f = lane + 64 * u;
    int blk = f >> 5, rr = (f >> 2) & 7;
    float acc;
    if (blk == 0) {
      acc = se0 * sG[(0 + rr) * 36 + 35] + se1 * sG[(8 + rr) * 36 + 35] + se2 * sG[(16 + rr) * 36 + 35];
    } else {
      int c0 = d_L6[blk - 1], c1 = d_L6[blk];
      acc = 0.0f;
      for (int cc = c0; cc < c1; cc++) {
        float A = se0 * sG[(0 + rr) * 36 + cc] + se1 * sG[(8 + rr) * 36 + cc] + se2 * sG[(16 + rr) * 36 + cc];
        acc += d_NM[cc] * A * A;
      }
    }
    fout[u] = acc;
  }
  #pragma unroll
  for (int u = 0; u < 3; u++) sFeat[lane + 64 * u] = fout[u];

  // MLP layer 1: 192 -> 64
  {
    float a0v = 0.f, a1 = 0.f, a2 = 0.f, a3 = 0.f;
    for (int k4 = 0; k4 < 48; k4++) {
      float4 f4 = *(const float4*)(sFeat + k4 * 4);
      const float* w = Wa1 + (k4 * 4) * 64 + lane;
      a0v += f4.x * w[0];
      a1  += f4.y * w[64];
      a2  += f4.z * w[128];
      a3  += f4.w * w[192];
    }
    sH[lane] = siluf(a0v + a1 + a2 + a3 + ba1[lane]);
  }

  // MLP layer 2: 64 -> 64, layer 3 + wave reduction
  {
    float a0v = 0.f, a1 = 0.f, a2 = 0.f, a3 = 0.f;
    for (int k4 = 0; k4 < 16; k4++) {
      float4 h4 = *(const float4*)(sH + k4 * 4);
      const float* w = Wa2 + (k4 * 4) * 64 + lane;
      a0v += h4.x * w[0];
      a1  += h4.y * w[64];
      a2  += h4.z * w[128];
      a3  += h4.w * w[192];
    }
    float h2 = siluf(a0v + a1 + a2 + a3 + ba2[lane]);
    float pr = h2 * Wa3[lane];
    #pragma unroll
    for (int off = 32; off > 0; off >>= 1) pr += __shfl_down(pr, off, 64);
    if (lane == 0) out[a] = pr + ba3[0];
  }
}

extern "C" void kernel_launch(void* const* d_in, const int* in_sizes, int n_in,
                              void* d_out, int out_size, void* d_ws, size_t ws_size,
                              hipStream_t stream)
{
  const float* rij         = (const float*)d_in[0];
  const int*   species     = (const int*)  d_in[1];
  const int*   first_atom  = (const int*)  d_in[2];
  const int*   second_atom = (const int*)  d_in[3];
  const float* Wr1 = (const float*)d_in[4];
  const float* br1 = (const float*)d_in[5];
  const float* Wr2 = (const float*)d_in[6];
  const float* br2 = (const float*)d_in[7];
  const float* Ws1 = (const float*)d_in[8];
  const float* bs1 = (const float*)d_in[9];
  const float* Ws2 = (const float*)d_in[10];
  const float* bs2 = (const float*)d_in[11];
  const float* Wa1 = (const float*)d_in[12];
  const float* ba1 = (const float*)d_in[13];
  const float* Wa2 = (const float*)d_in[14];
  const float* ba2 = (const float*)d_in[15];
  const float* Wa3 = (const float*)d_in[16];
  const float* ba3 = (const float*)d_in[17];
  float* ws  = (float*)d_ws;
  float* out = (float*)d_out;

  k_init<<<40, 256, 0, stream>>>(Ws1, bs1, Ws2, bs2, ws);
  k_hist<<<(NEDGES + 255) / 256, 256, 0, stream>>>(first_atom, ws);
  k_alloc<<<40, 256, 0, stream>>>(ws);
  k_scatter<<<(NEDGES + 255) / 256, 256, 0, stream>>>(first_atom, second_atom, species, ws);
  k_fused<<<NATOMS / 4, 256, 0, stream>>>(rij, Wr1, br1, Wr2, br2,
                                          Wa1, ba1, Wa2, ba2, Wa3, ba3, ws, out);
}

// Round 14
// 229.892 us; speedup vs baseline: 1.4854x; 1.4854x over previous
//
#include <hip/hip_runtime.h>
#include <math.h>

#define NATOMS 10000
#define NEDGES 320000
#define RC_F 5.0f
#define PI_F 3.14159265358979323846f

// ---- workspace layout (in floats) ----
#define WS_SEMB   0         // 12 floats
#define WS_GTOT   12        // 1 int global allocation cursor
#define WS_CNT    16        // NATOMS ints
#define WS_OFFS   10016     // NATOMS ints (run start per atom)
#define WS_CURSOR 20016     // NATOMS ints
#define WS_EIDX   30016     // NEDGES ints: packed (t<<20)|e per atom-run
#define WS_SA     350080    // NEDGES*32 floats: R[0..23] (+pad), 128B records, slot = edge id
#define WS_SB     10590080  // NEDGES*32 floats: R[24..47], rhat (+pad), 128B records

// multinomial term tables (global component index 0..34)
__device__ __constant__ int   d_PWA[35] = {0, 0,0,1, 0,0,0,1,1,2, 0,0,0,0,1,1,1,2,2,3, 0,0,0,0,0,1,1,1,1,2,2,2,3,3,4};
__device__ __constant__ int   d_PWB[35] = {0, 0,1,0, 0,1,2,0,1,0, 0,1,2,3,0,1,2,0,1,0, 0,1,2,3,4,0,1,2,3,0,1,2,0,1,0};
__device__ __constant__ int   d_PWC[35] = {0, 1,0,0, 2,1,0,1,0,0, 3,2,1,0,2,1,0,1,0,0, 4,3,2,1,0,3,2,1,0,2,1,0,1,0,0};
__device__ __constant__ float d_NM[35]  = {1.f, 1.f,1.f,1.f, 1.f,2.f,1.f,2.f,2.f,1.f,
                                           1.f,3.f,3.f,1.f,3.f,6.f,3.f,3.f,3.f,1.f,
                                           1.f,4.f,6.f,4.f,1.f,4.f,12.f,12.f,4.f,6.f,12.f,6.f,4.f,4.f,1.f};
__device__ __constant__ int   d_LBLK[35]= {0, 1,1,1, 2,2,2,2,2,2, 3,3,3,3,3,3,3,3,3,3, 4,4,4,4,4,4,4,4,4,4,4,4,4,4,4};
__device__ __constant__ int   d_L6[6]   = {0,1,4,10,20,35};

__device__ __forceinline__ float siluf(float x) { return x / (1.0f + __expf(-x)); }

__device__ __forceinline__ float2 f2fma(float2 a, float2 b, float2 c) {
  return make_float2(fmaf(a.x, b.x, c.x), fmaf(a.y, b.y, c.y));
}

__device__ __forceinline__ float psel(float x, int p) {
  float x2 = x * x;
  float r = 1.0f;
  r = (p == 1) ? x : r;
  r = (p == 2) ? x2 : r;
  r = (p == 3) ? x2 * x : r;
  r = (p == 4) ? x2 * x2 : r;
  return r;
}

// ---------------- k_init ----------------
__global__ void k_init(const float* __restrict__ Ws1, const float* __restrict__ bs1,
                       const float* __restrict__ Ws2, const float* __restrict__ bs2,
                       float* __restrict__ ws)
{
  int tid = blockIdx.x * blockDim.x + threadIdx.x;
  int* cnt = (int*)(ws + WS_CNT);
  if (tid < NATOMS) cnt[tid] = 0;
  if (tid == 0) *(int*)(ws + WS_GTOT) = 0;
  if (tid < 12) {
    int t = tid >> 2, s = tid & 3;
    float acc = bs2[s];
    for (int j = 0; j < 16; j++) acc += tanhf(Ws1[t * 16 + j] + bs1[j]) * Ws2[j * 4 + s];
    ws[WS_SEMB + tid] = acc;
  }
}

// ---------------- k_hist ----------------
__global__ void k_hist(const int* __restrict__ first_atom, float* __restrict__ ws)
{
  int e = blockIdx.x * blockDim.x + threadIdx.x;
  if (e < NEDGES) {
    int* cnt = (int*)(ws + WS_CNT);
    atomicAdd(&cnt[first_atom[e]], 1);
  }
}

// ---------------- k_alloc ----------------
__global__ __launch_bounds__(256) void k_alloc(float* __restrict__ ws)
{
  const int* cnt = (const int*)(ws + WS_CNT);
  int* offs   = (int*)(ws + WS_OFFS);
  int* cursor = (int*)(ws + WS_CURSOR);
  int* gtot = (int*)(ws + WS_GTOT);
  __shared__ int wsum[4];
  __shared__ int sbase;
  int tid = threadIdx.x;
  int lane = tid & 63, wv = tid >> 6;
  int a = blockIdx.x * 256 + tid;
  bool live = (a < NATOMS);
  int c = live ? cnt[a] : 0;
  int inc = c;
  #pragma unroll
  for (int d = 1; d < 64; d <<= 1) {
    int v = __shfl_up(inc, d, 64);
    if (lane >= d) inc += v;
  }
  if (lane == 63) wsum[wv] = inc;
  __syncthreads();
  if (tid == 0) sbase = atomicAdd(gtot, wsum[0] + wsum[1] + wsum[2] + wsum[3]);
  __syncthreads();
  int woff = sbase;
  for (int w = 0; w < wv; w++) woff += wsum[w];
  int o0 = woff + inc - c;
  if (live) { offs[a] = o0; cursor[a] = o0; }
}

// ---------------- k_edge: packed-FMA MLP -> half-record LDS rows -> 2 coalesced bursts ----------------
__global__ __launch_bounds__(256) void k_edge(
    const float* __restrict__ rij, const int* __restrict__ species,
    const int* __restrict__ first_atom, const int* __restrict__ second_atom,
    const float* __restrict__ Wr1, const float* __restrict__ br1,
    const float* __restrict__ Wr2, const float* __restrict__ br2,
    float* __restrict__ ws)
{
  __shared__ __align__(16) float sRec[4][64 * 28];   // 28 KB/block
  int tid = threadIdx.x, lane = tid & 63, wv = tid >> 6;
  int e = blockIdx.x * 256 + tid;                    // NEDGES = 1250*256 exact
  int* cursor = (int*)(ws + WS_CURSOR);
  int* eidx   = (int*)(ws + WS_EIDX);
  float* myrow = &sRec[wv][lane * 28];

  // gather chain + atomic + eidx store early; latency overlaps the MLP
  int a = first_atom[e];
  int t = species[second_atom[e]];
  int pos = atomicAdd(&cursor[a], 1);
  eidx[pos] = e | (t << 20);

  float x = rij[e * 3 + 0], y = rij[e * 3 + 1], z = rij[e * 3 + 2];
  float d = sqrtf(x * x + y * y + z * z + 1e-12f);
  float invd = 1.0f / d;

  // one sin+cos; Chebyshev recurrence for sin(n*theta); fc shares cos(theta)
  float theta = (PI_F / RC_F) * d;
  float s1 = __sinf(theta), c1 = __cosf(theta);
  float fc = (d < RC_F) ? 0.5f * (c1 + 1.0f) : 0.0f;
  float bes[8];
  {
    float sq = sqrtf(2.0f / RC_F) * invd;
    float twoc = 2.0f * c1;
    float sp = 0.0f, sc = s1;
    #pragma unroll
    for (int k = 0; k < 8; k++) {
      bes[k] = sq * sc;
      float sn = twoc * sc - sp;
      sp = sc; sc = sn;
    }
  }

  // layer 1: 8 -> 64, packed float2 (weights wave-uniform -> SGPR pairs)
  float h1[64];
  #pragma unroll
  for (int j4 = 0; j4 < 16; j4++) {
    float2 a01 = *(const float2*)&br1[j4 * 4];
    float2 a23 = *(const float2*)&br1[j4 * 4 + 2];
    #pragma unroll
    for (int k = 0; k < 8; k++) {
      float2 b2 = make_float2(bes[k], bes[k]);
      a01 = f2fma(b2, *(const float2*)&Wr1[k * 64 + j4 * 4],     a01);
      a23 = f2fma(b2, *(const float2*)&Wr1[k * 64 + j4 * 4 + 2], a23);
    }
    h1[j4 * 4 + 0] = siluf(a01.x);
    h1[j4 * 4 + 1] = siluf(a01.y);
    h1[j4 * 4 + 2] = siluf(a23.x);
    h1[j4 * 4 + 3] = siluf(a23.y);
  }

  int ebase = blockIdx.x * 256 + wv * 64;            // first edge of this wave
  const float* buf = &sRec[wv][0];
  int f4 = lane & 7;

  // ---- phase A: outputs 0..23 (packed) ----
  for (int j4 = 0; j4 < 6; j4++) {
    float2 a01 = *(const float2*)&br2[j4 * 4];
    float2 a23 = *(const float2*)&br2[j4 * 4 + 2];
    #pragma unroll
    for (int k = 0; k < 64; k++) {
      float2 h2 = make_float2(h1[k], h1[k]);
      a01 = f2fma(h2, *(const float2*)&Wr2[k * 48 + j4 * 4],     a01);
      a23 = f2fma(h2, *(const float2*)&Wr2[k * 48 + j4 * 4 + 2], a23);
    }
    *(float4*)(myrow + j4 * 4) = make_float4(siluf(a01.x) * fc, siluf(a01.y) * fc,
                                             siluf(a23.x) * fc, siluf(a23.y) * fc);
  }
  {
    float* gbase = ws + WS_SA + (size_t)ebase * 32;
    if (f4 < 6) {
      #pragma unroll
      for (int q = 0; q < 8; q++) {
        int g4 = q * 64 + lane;
        float4 v = *(const float4*)(buf + (g4 >> 3) * 28 + f4 * 4);
        *(float4*)(gbase + (size_t)g4 * 4) = v;
      }
    }
  }

  // ---- phase B: outputs 24..47 + rhat (LDS rows reused; same-wave DS order safe) ----
  for (int j4 = 6; j4 < 12; j4++) {
    float2 a01 = *(const float2*)&br2[j4 * 4];
    float2 a23 = *(const float2*)&br2[j4 * 4 + 2];
    #pragma unroll
    for (int k = 0; k < 64; k++) {
      float2 h2 = make_float2(h1[k], h1[k]);
      a01 = f2fma(h2, *(const float2*)&Wr2[k * 48 + j4 * 4],     a01);
      a23 = f2fma(h2, *(const float2*)&Wr2[k * 48 + j4 * 4 + 2], a23);
    }
    *(float4*)(myrow + (j4 - 6) * 4) = make_float4(siluf(a01.x) * fc, siluf(a01.y) * fc,
                                                   siluf(a23.x) * fc, siluf(a23.y) * fc);
  }
  *(float4*)(myrow + 24) = make_float4(x * invd, y * invd, z * invd, 0.0f);
  {
    float* gbase = ws + WS_SB + (size_t)ebase * 32;
    if (f4 < 7) {
      #pragma unroll
      for (int q = 0; q < 8; q++) {
        int g4 = q * 64 + lane;
        float4 v = *(const float4*)(buf + (g4 >> 3) * 28 + f4 * 4);
        *(float4*)(gbase + (size_t)g4 * 4) = v;
      }
    }
  }
}

// ---------------- k_atom: one wave per atom, depth-2 prefetch, BRANCH-FREE select-FMA CORE ----------------
__global__ __launch_bounds__(128) void k_atom(
    const float* __restrict__ ws,
    const float* __restrict__ Wa1, const float* __restrict__ ba1,
    const float* __restrict__ Wa2, const float* __restrict__ ba2,
    const float* __restrict__ Wa3, const float* __restrict__ ba3,
    float* __restrict__ out)
{
  // per-wave: [0..767] triple-buffered 4-record stage, [768..1631] G (col 35 = G0),
  //           [1632..1823] feat, [1824..1887] h
  __shared__ __align__(16) float sScr[2][1920];
  int tid = threadIdx.x;
  int lane = tid & 63, wv = tid >> 6;
  int a = blockIdx.x * 2 + wv;          // NATOMS = 5000*2 exact
  float* sStage = &sScr[wv][0];
  float* sG     = &sScr[wv][768];
  float* sFeat  = &sScr[wv][1632];
  float* sH     = &sScr[wv][1824];

  const int* offs = (const int*)(ws + WS_OFFS);
  const int* cnt  = (const int*)(ws + WS_CNT);
  const int* eidx = (const int*)(ws + WS_EIDX);
  int start = offs[a], len = cnt[a], end = start + len;

  const int c = lane;
  bool isc = (c < 35);
  int pa = 0, pb = 0, pcw = 0, lb = 0;
  if (isc) { pa = d_PWA[c]; pb = d_PWB[c]; pcw = d_PWC[c]; lb = d_LBLK[c]; }
  int rdir = lane - 35;
  bool isd = (rdir >= 0) && (rdir < 8);
  int rl = lane >> 4, fl = lane & 15;   // gather role: record rl, float4 fl
  const float* gsrc = ws + (fl < 6 ? WS_SA : WS_SB);
  int foff = (fl < 6) ? fl : ((fl < 13) ? fl - 6 : 6);

  float2 g2[3][4];
  #pragma unroll
  for (int t2 = 0; t2 < 3; t2++)
    #pragma unroll
    for (int r = 0; r < 4; r++) g2[t2][r] = make_float2(0.f, 0.f);
  float g0[3] = {0.0f, 0.0f, 0.0f};

// Branch-free: select comp into the right species bank via cndmask, then 24
// unconditional FMAs. No readfirstlane, no branches -> iterations fully
// independent, LDS reads pipeline across the loop.
#define CORE() {                                                              \
    int tv = __shfl(packed, g + j, 64) >> 20;                                 \
    const float* rb = buf + j * 64;                                           \
    if (isc) {                                                                \
      float comp = psel(rb[48], pa) * psel(rb[49], pb) * psel(rb[50], pcw);   \
      float cm0 = (tv == 0) ? comp : 0.0f;                                    \
      float cm1 = (tv == 1) ? comp : 0.0f;                                    \
      float cm2 = (tv == 2) ? comp : 0.0f;                                    \
      const float2* r2 = (const float2*)(rb + 8 + 8 * lb);                    \
      float2 q0 = r2[0], q1 = r2[1], q2 = r2[2], q3 = r2[3];                  \
      float2 v0 = make_float2(cm0, cm0), v1 = make_float2(cm1, cm1),          \
             v2 = make_float2(cm2, cm2);                                      \
      g2[0][0] = f2fma(v0, q0, g2[0][0]); g2[0][1] = f2fma(v0, q1, g2[0][1]); \
      g2[0][2] = f2fma(v0, q2, g2[0][2]); g2[0][3] = f2fma(v0, q3, g2[0][3]); \
      g2[1][0] = f2fma(v1, q0, g2[1][0]); g2[1][1] = f2fma(v1, q1, g2[1][1]); \
      g2[1][2] = f2fma(v1, q2, g2[1][2]); g2[1][3] = f2fma(v1, q3, g2[1][3]); \
      g2[2][0] = f2fma(v2, q0, g2[2][0]); g2[2][1] = f2fma(v2, q1, g2[2][1]); \
      g2[2][2] = f2fma(v2, q2, g2[2][2]); g2[2][3] = f2fma(v2, q3, g2[2][3]); \
    } else if (isd) {                                                         \
      float v = rb[rdir];                                                     \
      g0[0] += (tv == 0) ? v : 0.0f;                                          \
      g0[1] += (tv == 1) ? v : 0.0f;                                          \
      g0[2] += (tv == 2) ? v : 0.0f;                                          \
    }                                                                         \
  }

#define LOADR(Q, DST) {                                                       \
    int sl_ = (Q) * 4 + rl; if (sl_ >= m) sl_ = m - 1;                        \
    int pk_ = __shfl(packed, sl_, 64);                                        \
    DST = *(const float4*)(gsrc + (size_t)(pk_ & 0xFFFFF) * 32 + foff * 4);   \
  }

  for (int cb = start; cb < end; cb += 64) {
    int m = end - cb; if (m > 64) m = 64;
    int pp = cb + lane;
    int packed = eidx[pp < end ? pp : start];     // coalesced chunk of indices
    int R = (m + 3) >> 2;
    float4 v0, v1;
    LOADR(0, v0)
    if (R > 1) { LOADR(1, v1) } else v1 = v0;
    int bsel = 0;
    for (int r = 0; r < R; r++) {
      float* buf = sStage + (bsel << 8);
      bsel = (bsel == 2) ? 0 : bsel + 1;
      *(float4*)(buf + rl * 64 + fl * 4) = v0;    // ds_write staged round
      v0 = v1;
      if (r + 2 < R) LOADR(r + 2, v1)             // keep 2 loads in flight
      int g = r * 4, gm = m - g; if (gm > 4) gm = 4;
      for (int j = 0; j < gm; j++) CORE()
    }
  }
#undef CORE
#undef LOADR

  // transpose G into LDS (same-wave, no barrier)
  if (isc) {
    #pragma unroll
    for (int t2 = 0; t2 < 3; t2++)
      #pragma unroll
      for (int r = 0; r < 8; r++) {
        float gval = (r & 1) ? g2[t2][r >> 1].y : g2[t2][r >> 1].x;
        sG[(t2 * 8 + r) * 36 + c] = gval;
      }
  } else if (isd) {
    #pragma unroll
    for (int t2 = 0; t2 < 3; t2++) sG[(t2 * 8 + rdir) * 36 + 35] = g0[t2];
  }

  // contraction: lane owns feats {lane, lane+64, lane+128}; f=(blk*8+rr)*4+s
  int s = lane & 3;
  float se0 = ws[WS_SEMB + s], se1 = ws[WS_SEMB + 4 + s], se2 = ws[WS_SEMB + 8 + s];
  float fout[3];
  #pragma unroll
  for (int u = 0; u < 3; u++) {
    int f = lane + 64 * u;
    int blk = f >> 5, rr = (f >> 2) & 7;
    float acc;
    if (blk == 0) {
      acc = se0 * sG[(0 + rr) * 36 + 35] + se1 * sG[(8 + rr) * 36 + 35] + se2 * sG[(16 + rr) * 36 + 35];
    } else {
      int c0 = d_L6[blk - 1], c1 = d_L6[blk];
      acc = 0.0f;
      for (int cc = c0; cc < c1; cc++) {
        float A = se0 * sG[(0 + rr) * 36 + cc] + se1 * sG[(8 + rr) * 36 + cc] + se2 * sG[(16 + rr) * 36 + cc];
        acc += d_NM[cc] * A * A;
      }
    }
    fout[u] = acc;
  }
  #pragma unroll
  for (int u = 0; u < 3; u++) sFeat[lane + 64 * u] = fout[u];

  // MLP layer 1: 192 -> 64
  {
    float a0 = 0.f, a1 = 0.f, a2 = 0.f, a3 = 0.f;
    for (int k4 = 0; k4 < 48; k4++) {
      float4 f4 = *(const float4*)(sFeat + k4 * 4);
      const float* w = Wa1 + (k4 * 4) * 64 + lane;
      a0 += f4.x * w[0];
      a1 += f4.y * w[64];
      a2 += f4.z * w[128];
      a3 += f4.w * w[192];
    }
    sH[lane] = siluf(a0 + a1 + a2 + a3 + ba1[lane]);
  }

  // MLP layer 2: 64 -> 64, layer 3 + wave reduction
  {
    float a0 = 0.f, a1 = 0.f, a2 = 0.f, a3 = 0.f;
    for (int k4 = 0; k4 < 16; k4++) {
      float4 h4 = *(const float4*)(sH + k4 * 4);
      const float* w = Wa2 + (k4 * 4) * 64 + lane;
      a0 += h4.x * w[0];
      a1 += h4.y * w[64];
      a2 += h4.z * w[128];
      a3 += h4.w * w[192];
    }
    float h2 = siluf(a0 + a1 + a2 + a3 + ba2[lane]);
    float pr = h2 * Wa3[lane];
    #pragma unroll
    for (int off = 32; off > 0; off >>= 1) pr += __shfl_down(pr, off, 64);
    if (lane == 0) out[a] = pr + ba3[0];
  }
}

extern "C" void kernel_launch(void* const* d_in, const int* in_sizes, int n_in,
                              void* d_out, int out_size, void* d_ws, size_t ws_size,
                              hipStream_t stream)
{
  const float* rij         = (const float*)d_in[0];
  const int*   species     = (const int*)  d_in[1];
  const int*   first_atom  = (const int*)  d_in[2];
  const int*   second_atom = (const int*)  d_in[3];
  const float* Wr1 = (const float*)d_in[4];
  const float* br1 = (const float*)d_in[5];
  const float* Wr2 = (const float*)d_in[6];
  const float* br2 = (const float*)d_in[7];
  const float* Ws1 = (const float*)d_in[8];
  const float* bs1 = (const float*)d_in[9];
  const float* Ws2 = (const float*)d_in[10];
  const float* bs2 = (const float*)d_in[11];
  const float* Wa1 = (const float*)d_in[12];
  const float* ba1 = (const float*)d_in[13];
  const float* Wa2 = (const float*)d_in[14];
  const float* ba2 = (const float*)d_in[15];
  const float* Wa3 = (const float*)d_in[16];
  const float* ba3 = (const float*)d_in[17];
  float* ws  = (float*)d_ws;
  float* out = (float*)d_out;

  k_init<<<40, 256, 0, stream>>>(Ws1, bs1, Ws2, bs2, ws);
  k_hist<<<(NEDGES + 255) / 256, 256, 0, stream>>>(first_atom, ws);
  k_alloc<<<40, 256, 0, stream>>>(ws);
  k_edge<<<NEDGES / 256, 256, 0, stream>>>(rij, species, first_atom, second_atom,
                                           Wr1, br1, Wr2, br2, ws);
  k_atom<<<NATOMS / 2, 128, 0, stream>>>(ws, Wa1, ba1, Wa2, ba2, Wa3, ba3, out);
}

// Round 15
// 213.836 us; speedup vs baseline: 1.5970x; 1.0751x over previous
//
#include <hip/hip_runtime.h>
#include <math.h>

#define NATOMS 10000
#define NEDGES 320000
#define NBINS  (NATOMS * 4)   // bin = atom*4 + species; bin a*4+3 always empty
#define RC_F 5.0f
#define PI_F 3.14159265358979323846f

// ---- workspace layout (in floats) ----
#define WS_SEMB   0         // 12 floats
#define WS_GTOT   12        // 1 int global allocation cursor
#define WS_CNT    16        // NBINS ints
#define WS_OFFS   40016     // NBINS ints (int4/atom: run starts t=0,1,2 + end)
#define WS_CURSOR 80016     // NBINS ints
#define WS_EIDX   120016    // NEDGES ints: edge id, (atom,species)-sorted
#define WS_SA     440096    // NEDGES*32 floats: R[0..23] (+pad), 128B recs (base 128B-aligned)
#define WS_SB     10680096  // NEDGES*32 floats: R[24..47], rhat (+pad)

// multinomial term tables (global component index 0..34)
__device__ __constant__ int   d_PWA[35] = {0, 0,0,1, 0,0,0,1,1,2, 0,0,0,0,1,1,1,2,2,3, 0,0,0,0,0,1,1,1,1,2,2,2,3,3,4};
__device__ __constant__ int   d_PWB[35] = {0, 0,1,0, 0,1,2,0,1,0, 0,1,2,3,0,1,2,0,1,0, 0,1,2,3,4,0,1,2,3,0,1,2,0,1,0};
__device__ __constant__ int   d_PWC[35] = {0, 1,0,0, 2,1,0,1,0,0, 3,2,1,0,2,1,0,1,0,0, 4,3,2,1,0,3,2,1,0,2,1,0,1,0,0};
__device__ __constant__ float d_NM[35]  = {1.f, 1.f,1.f,1.f, 1.f,2.f,1.f,2.f,2.f,1.f,
                                           1.f,3.f,3.f,1.f,3.f,6.f,3.f,3.f,3.f,1.f,
                                           1.f,4.f,6.f,4.f,1.f,4.f,12.f,12.f,4.f,6.f,12.f,6.f,4.f,4.f,1.f};
__device__ __constant__ int   d_LBLK[35]= {0, 1,1,1, 2,2,2,2,2,2, 3,3,3,3,3,3,3,3,3,3, 4,4,4,4,4,4,4,4,4,4,4,4,4,4,4};
__device__ __constant__ int   d_L6[6]   = {0,1,4,10,20,35};

__device__ __forceinline__ float siluf(float x) { return x / (1.0f + __expf(-x)); }

__device__ __forceinline__ float2 f2fma(float2 a, float2 b, float2 c) {
  return make_float2(fmaf(a.x, b.x, c.x), fmaf(a.y, b.y, c.y));
}

__device__ __forceinline__ float psel(float x, int p) {
  float x2 = x * x;
  float r = 1.0f;
  r = (p == 1) ? x : r;
  r = (p == 2) ? x2 : r;
  r = (p == 3) ? x2 * x : r;
  r = (p == 4) ? x2 * x2 : r;
  return r;
}

// ---------------- k_init ----------------
__global__ void k_init(const float* __restrict__ Ws1, const float* __restrict__ bs1,
                       const float* __restrict__ Ws2, const float* __restrict__ bs2,
                       float* __restrict__ ws)
{
  int tid = blockIdx.x * blockDim.x + threadIdx.x;
  int* cnt = (int*)(ws + WS_CNT);
  if (tid < NBINS) cnt[tid] = 0;
  if (tid == 0) *(int*)(ws + WS_GTOT) = 0;
  if (tid < 12) {
    int t = tid >> 2, s = tid & 3;
    float acc = bs2[s];
    for (int j = 0; j < 16; j++) acc += tanhf(Ws1[t * 16 + j] + bs1[j]) * Ws2[j * 4 + s];
    ws[WS_SEMB + tid] = acc;
  }
}

// ---------------- k_hist: (atom,species)-bin counts ----------------
__global__ void k_hist(const int* __restrict__ first_atom, const int* __restrict__ second_atom,
                       const int* __restrict__ species, float* __restrict__ ws)
{
  int e = blockIdx.x * blockDim.x + threadIdx.x;
  if (e < NEDGES) {
    int* cnt = (int*)(ws + WS_CNT);
    int bin = first_atom[e] * 4 + species[second_atom[e]];
    atomicAdd(&cnt[bin], 1);
  }
}

// ---------------- k_alloc: decentralized run allocation, int4 per atom ----------------
// Each atom's 4 bins get a contiguous in-order run -> k_atom's species runs are
// contiguous and species-homogeneous.
__global__ __launch_bounds__(256) void k_alloc(float* __restrict__ ws)
{
  const int4* cnt4 = (const int4*)(ws + WS_CNT);
  int4* offs4   = (int4*)(ws + WS_OFFS);
  int4* cursor4 = (int4*)(ws + WS_CURSOR);
  int* gtot = (int*)(ws + WS_GTOT);
  __shared__ int wsum[4];
  __shared__ int sbase;
  int tid = threadIdx.x;
  int lane = tid & 63, wv = tid >> 6;
  int a = blockIdx.x * 256 + tid;
  bool live = (a < NATOMS);
  int4 c = live ? cnt4[a] : make_int4(0, 0, 0, 0);
  int s = c.x + c.y + c.z + c.w;          // c.w == 0 always
  int inc = s;
  #pragma unroll
  for (int d = 1; d < 64; d <<= 1) {
    int v = __shfl_up(inc, d, 64);
    if (lane >= d) inc += v;
  }
  if (lane == 63) wsum[wv] = inc;
  __syncthreads();
  if (tid == 0) sbase = atomicAdd(gtot, wsum[0] + wsum[1] + wsum[2] + wsum[3]);
  __syncthreads();
  int woff = sbase;
  for (int w = 0; w < wv; w++) woff += wsum[w];
  int o0 = woff + inc - s;
  if (live) {
    int4 o;
    o.x = o0;
    o.y = o.x + c.x;
    o.z = o.y + c.y;
    o.w = o.z + c.z;                      // end of atom's whole run
    offs4[a] = o;
    cursor4[a] = o;
  }
}

// ---------------- k_edge: packed-FMA MLP -> half-record LDS rows -> 2 coalesced bursts ----------------
__global__ __launch_bounds__(256) void k_edge(
    const float* __restrict__ rij, const int* __restrict__ species,
    const int* __restrict__ first_atom, const int* __restrict__ second_atom,
    const float* __restrict__ Wr1, const float* __restrict__ br1,
    const float* __restrict__ Wr2, const float* __restrict__ br2,
    float* __restrict__ ws)
{
  __shared__ __align__(16) float sRec[4][64 * 28];   // 28 KB/block
  int tid = threadIdx.x, lane = tid & 63, wv = tid >> 6;
  int e = blockIdx.x * 256 + tid;                    // NEDGES = 1250*256 exact
  int* cursor = (int*)(ws + WS_CURSOR);
  int* eidx   = (int*)(ws + WS_EIDX);
  float* myrow = &sRec[wv][lane * 28];

  // gather chain + atomic + eidx store early; latency overlaps the MLP
  int a = first_atom[e];
  int t = species[second_atom[e]];
  int pos = atomicAdd(&cursor[a * 4 + t], 1);
  eidx[pos] = e;

  float x = rij[e * 3 + 0], y = rij[e * 3 + 1], z = rij[e * 3 + 2];
  float d = sqrtf(x * x + y * y + z * z + 1e-12f);
  float invd = 1.0f / d;

  // one sin+cos; Chebyshev recurrence for sin(n*theta); fc shares cos(theta)
  float theta = (PI_F / RC_F) * d;
  float s1 = __sinf(theta), c1 = __cosf(theta);
  float fc = (d < RC_F) ? 0.5f * (c1 + 1.0f) : 0.0f;
  float bes[8];
  {
    float sq = sqrtf(2.0f / RC_F) * invd;
    float twoc = 2.0f * c1;
    float sp = 0.0f, sc = s1;
    #pragma unroll
    for (int k = 0; k < 8; k++) {
      bes[k] = sq * sc;
      float sn = twoc * sc - sp;
      sp = sc; sc = sn;
    }
  }

  // layer 1: 8 -> 64, packed float2 (weights wave-uniform)
  float h1[64];
  #pragma unroll
  for (int j4 = 0; j4 < 16; j4++) {
    float2 a01 = *(const float2*)&br1[j4 * 4];
    float2 a23 = *(const float2*)&br1[j4 * 4 + 2];
    #pragma unroll
    for (int k = 0; k < 8; k++) {
      float2 b2 = make_float2(bes[k], bes[k]);
      a01 = f2fma(b2, *(const float2*)&Wr1[k * 64 + j4 * 4],     a01);
      a23 = f2fma(b2, *(const float2*)&Wr1[k * 64 + j4 * 4 + 2], a23);
    }
    h1[j4 * 4 + 0] = siluf(a01.x);
    h1[j4 * 4 + 1] = siluf(a01.y);
    h1[j4 * 4 + 2] = siluf(a23.x);
    h1[j4 * 4 + 3] = siluf(a23.y);
  }

  int ebase = blockIdx.x * 256 + wv * 64;            // first edge of this wave
  const float* buf = &sRec[wv][0];
  int f4 = lane & 7;

  // ---- phase A: outputs 0..23 ----
  for (int j4 = 0; j4 < 6; j4++) {
    float2 a01 = *(const float2*)&br2[j4 * 4];
    float2 a23 = *(const float2*)&br2[j4 * 4 + 2];
    #pragma unroll
    for (int k = 0; k < 64; k++) {
      float2 h2 = make_float2(h1[k], h1[k]);
      a01 = f2fma(h2, *(const float2*)&Wr2[k * 48 + j4 * 4],     a01);
      a23 = f2fma(h2, *(const float2*)&Wr2[k * 48 + j4 * 4 + 2], a23);
    }
    *(float4*)(myrow + j4 * 4) = make_float4(siluf(a01.x) * fc, siluf(a01.y) * fc,
                                             siluf(a23.x) * fc, siluf(a23.y) * fc);
  }
  {
    float* gbase = ws + WS_SA + (size_t)ebase * 32;
    if (f4 < 6) {
      #pragma unroll
      for (int q = 0; q < 8; q++) {
        int g4 = q * 64 + lane;
        float4 v = *(const float4*)(buf + (g4 >> 3) * 28 + f4 * 4);
        *(float4*)(gbase + (size_t)g4 * 4) = v;
      }
    }
  }

  // ---- phase B: outputs 24..47 + rhat ----
  for (int j4 = 6; j4 < 12; j4++) {
    float2 a01 = *(const float2*)&br2[j4 * 4];
    float2 a23 = *(const float2*)&br2[j4 * 4 + 2];
    #pragma unroll
    for (int k = 0; k < 64; k++) {
      float2 h2 = make_float2(h1[k], h1[k]);
      a01 = f2fma(h2, *(const float2*)&Wr2[k * 48 + j4 * 4],     a01);
      a23 = f2fma(h2, *(const float2*)&Wr2[k * 48 + j4 * 4 + 2], a23);
    }
    *(float4*)(myrow + (j4 - 6) * 4) = make_float4(siluf(a01.x) * fc, siluf(a01.y) * fc,
                                                   siluf(a23.x) * fc, siluf(a23.y) * fc);
  }
  *(float4*)(myrow + 24) = make_float4(x * invd, y * invd, z * invd, 0.0f);
  {
    float* gbase = ws + WS_SB + (size_t)ebase * 32;
    if (f4 < 7) {
      #pragma unroll
      for (int q = 0; q < 8; q++) {
        int g4 = q * 64 + lane;
        float4 v = *(const float4*)(buf + (g4 >> 3) * 28 + f4 * 4);
        *(float4*)(gbase + (size_t)g4 * 4) = v;
      }
    }
  }
}

// ---------------- k_atom: one wave per atom, species-homogeneous runs, 8-FMA CORE ----------------
__global__ __launch_bounds__(128) void k_atom(
    const float* __restrict__ ws,
    const float* __restrict__ Wa1, const float* __restrict__ ba1,
    const float* __restrict__ Wa2, const float* __restrict__ ba2,
    const float* __restrict__ Wa3, const float* __restrict__ ba3,
    float* __restrict__ out)
{
  // per-wave: [0..767] triple-buffered 4-record stage, [768..1631] G (col 35 = G0),
  //           [1632..1823] feat, [1824..1887] h
  __shared__ __align__(16) float sScr[2][1920];
  int tid = threadIdx.x;
  int lane = tid & 63, wv = tid >> 6;
  int a = blockIdx.x * 2 + wv;          // NATOMS = 5000*2 exact
  float* sStage = &sScr[wv][0];
  float* sG     = &sScr[wv][768];
  float* sFeat  = &sScr[wv][1632];
  float* sH     = &sScr[wv][1824];

  const int* eidx = (const int*)(ws + WS_EIDX);
  int4 o = ((const int4*)(ws + WS_OFFS))[a];   // run starts t=0,1,2; o.w = end

  const int c = lane;
  bool isc = (c < 35);
  int pa = 0, pb = 0, pcw = 0, lb = 0;
  if (isc) { pa = d_PWA[c]; pb = d_PWB[c]; pcw = d_PWC[c]; lb = d_LBLK[c]; }
  int rdir = lane - 35;
  bool isd = (rdir >= 0) && (rdir < 8);
  int rl = lane >> 4, fl = lane & 15;   // gather role: record rl, float4 fl
  const float* gsrc = ws + (fl < 6 ? WS_SA : WS_SB);
  int foff = (fl < 6) ? fl : ((fl < 13) ? fl - 6 : 6);

  float2 g2[3][4];
  #pragma unroll
  for (int t2 = 0; t2 < 3; t2++)
    #pragma unroll
    for (int r = 0; r < 4; r++) g2[t2][r] = make_float2(0.f, 0.f);
  float g0[3] = {0.0f, 0.0f, 0.0f};

// species-homogeneous run: compile-time T, 8 FMAs, no shfl-for-t, no selects.
#define CORE(T) {                                                             \
    const float* rb = buf + j * 64;                                           \
    if (isc) {                                                                \
      float comp = psel(rb[48], pa) * psel(rb[49], pb) * psel(rb[50], pcw);   \
      float2 c2 = make_float2(comp, comp);                                    \
      const float2* r2 = (const float2*)(rb + 8 + 8 * lb);                    \
      g2[T][0] = f2fma(c2, r2[0], g2[T][0]);                                  \
      g2[T][1] = f2fma(c2, r2[1], g2[T][1]);                                  \
      g2[T][2] = f2fma(c2, r2[2], g2[T][2]);                                  \
      g2[T][3] = f2fma(c2, r2[3], g2[T][3]);                                  \
    } else if (isd) {                                                         \
      g0[T] += rb[rdir];                                                      \
    }                                                                         \
  }

#define LOADR(Q, DST) {                                                       \
    int sl_ = (Q) * 4 + rl; if (sl_ >= m) sl_ = m - 1;                        \
    int pk_ = __shfl(packed, sl_, 64);                                        \
    DST = *(const float4*)(gsrc + (size_t)pk_ * 32 + foff * 4);               \
  }

#define RUN(T, LO, HI)                                                        \
  for (int cb = (LO); cb < (HI); cb += 64) {                                  \
    int m = (HI) - cb; if (m > 64) m = 64;                                    \
    int pp = cb + lane;                                                       \
    int packed = eidx[pp < (HI) ? pp : (LO)];                                 \
    int R = (m + 3) >> 2;                                                     \
    float4 v0, v1;                                                            \
    LOADR(0, v0)                                                              \
    if (R > 1) { LOADR(1, v1) } else v1 = v0;                                 \
    int bsel = 0;                                                             \
    for (int r = 0; r < R; r++) {                                             \
      float* buf = sStage + (bsel << 8);                                      \
      bsel = (bsel == 2) ? 0 : bsel + 1;                                      \
      *(float4*)(buf + rl * 64 + fl * 4) = v0;                                \
      v0 = v1;                                                                \
      if (r + 2 < R) LOADR(r + 2, v1)                                         \
      int g = r * 4, gm = m - g; if (gm > 4) gm = 4;                          \
      for (int j = 0; j < gm; j++) CORE(T)                                    \
    }                                                                         \
  }

  RUN(0, o.x, o.y)
  RUN(1, o.y, o.z)
  RUN(2, o.z, o.w)
#undef RUN
#undef CORE
#undef LOADR

  // transpose G into LDS (same-wave, no barrier)
  if (isc) {
    #pragma unroll
    for (int t2 = 0; t2 < 3; t2++)
      #pragma unroll
      for (int r = 0; r < 8; r++) {
        float gval = (r & 1) ? g2[t2][r >> 1].y : g2[t2][r >> 1].x;
        sG[(t2 * 8 + r) * 36 + c] = gval;
      }
  } else if (isd) {
    #pragma unroll
    for (int t2 = 0; t2 < 3; t2++) sG[(t2 * 8 + rdir) * 36 + 35] = g0[t2];
  }

  // contraction: lane owns feats {lane, lane+64, lane+128}; f=(blk*8+rr)*4+s
  int s = lane & 3;
  float se0 = ws[WS_SEMB + s], se1 = ws[WS_SEMB + 4 + s], se2 = ws[WS_SEMB + 8 + s];
  float fout[3];
  #pragma unroll
  for (int u = 0; u < 3; u++) {
    int f = lane + 64 * u;
    int blk = f >> 5, rr = (f >> 2) & 7;
    float acc;
    if (blk == 0) {
      acc = se0 * sG[(0 + rr) * 36 + 35] + se1 * sG[(8 + rr) * 36 + 35] + se2 * sG[(16 + rr) * 36 + 35];
    } else {
      int c0 = d_L6[blk - 1], c1 = d_L6[blk];
      acc = 0.0f;
      for (int cc = c0; cc < c1; cc++) {
        float A = se0 * sG[(0 + rr) * 36 + cc] + se1 * sG[(8 + rr) * 36 + cc] + se2 * sG[(16 + rr) * 36 + cc];
        acc += d_NM[cc] * A * A;
      }
    }
    fout[u] = acc;
  }
  #pragma unroll
  for (int u = 0; u < 3; u++) sFeat[lane + 64 * u] = fout[u];

  // MLP layer 1: 192 -> 64
  {
    float a0 = 0.f, a1 = 0.f, a2 = 0.f, a3 = 0.f;
    for (int k4 = 0; k4 < 48; k4++) {
      float4 f4 = *(const float4*)(sFeat + k4 * 4);
      const float* w = Wa1 + (k4 * 4) * 64 + lane;
      a0 += f4.x * w[0];
      a1 += f4.y * w[64];
      a2 += f4.z * w[128];
      a3 += f4.w * w[192];
    }
    sH[lane] = siluf(a0 + a1 + a2 + a3 + ba1[lane]);
  }

  // MLP layer 2: 64 -> 64, layer 3 + wave reduction
  {
    float a0 = 0.f, a1 = 0.f, a2 = 0.f, a3 = 0.f;
    for (int k4 = 0; k4 < 16; k4++) {
      float4 h4 = *(const float4*)(sH + k4 * 4);
      const float* w = Wa2 + (k4 * 4) * 64 + lane;
      a0 += h4.x * w[0];
      a1 += h4.y * w[64];
      a2 += h4.z * w[128];
      a3 += h4.w * w[192];
    }
    float h2 = siluf(a0 + a1 + a2 + a3 + ba2[lane]);
    float pr = h2 * Wa3[lane];
    #pragma unroll
    for (int off = 32; off > 0; off >>= 1) pr += __shfl_down(pr, off, 64);
    if (lane == 0) out[a] = pr + ba3[0];
  }
}

extern "C" void kernel_launch(void* const* d_in, const int* in_sizes, int n_in,
                              void* d_out, int out_size, void* d_ws, size_t ws_size,
                              hipStream_t stream)
{
  const float* rij         = (const float*)d_in[0];
  const int*   species     = (const int*)  d_in[1];
  const int*   first_atom  = (const int*)  d_in[2];
  const int*   second_atom = (const int*)  d_in[3];
  const float* Wr1 = (const float*)d_in[4];
  const float* br1 = (const float*)d_in[5];
  const float* Wr2 = (const float*)d_in[6];
  const float* br2 = (const float*)d_in[7];
  const float* Ws1 = (const float*)d_in[8];
  const float* bs1 = (const float*)d_in[9];
  const float* Ws2 = (const float*)d_in[10];
  const float* bs2 = (const float*)d_in[11];
  const float* Wa1 = (const float*)d_in[12];
  const float* ba1 = (const float*)d_in[13];
  const float* Wa2 = (const float*)d_in[14];
  const float* ba2 = (const float*)d_in[15];
  const float* Wa3 = (const float*)d_in[16];
  const float* ba3 = (const float*)d_in[17];
  float* ws  = (float*)d_ws;
  float* out = (float*)d_out;

  k_init<<<(NBINS + 255) / 256, 256, 0, stream>>>(Ws1, bs1, Ws2, bs2, ws);
  k_hist<<<(NEDGES + 255) / 256, 256, 0, stream>>>(first_atom, second_atom, species, ws);
  k_alloc<<<(NATOMS + 255) / 256, 256, 0, stream>>>(ws);
  k_edge<<<NEDGES / 256, 256, 0, stream>>>(rij, species, first_atom, second_atom,
                                           Wr1, br1, Wr2, br2, ws);
  k_atom<<<NATOMS / 2, 128, 0, stream>>>(ws, Wa1, ba1, Wa2, ba2, Wa3, ba3, out);
}